// Round 5
// baseline (228.341 us; speedup 1.0000x reference)
//
#include <hip/hip_runtime.h>
#include <math.h>

#define HWSZ 4096
#define C_ 256
#define B_ 8

// ws layout (float offsets)
#define M_WS      0          // mask bf16: 8*256*4096 ushort = 4194304 floats
#define XB_WS     4194304    // x bf16 NHWC [b][hw][c]: 4194304 floats
#define WT2_WS    8388608    // (10*65536 + 9*32*256) ushort
#define SMEAN_WS  8753152    // 2048 (f channel sums)
#define SSCALE_WS 8755200    // 2048

typedef __attribute__((ext_vector_type(8))) short short8;
typedef __attribute__((ext_vector_type(4))) float f32x4;

__device__ __forceinline__ uint bfr(float a) {  // f32 -> bf16 bits (RNE)
  uint u = __float_as_uint(a);
  return (u + 0x7fffu + ((u >> 16) & 1u)) >> 16;
}
__device__ __forceinline__ uint pk2(float a, float b) { return bfr(a) | (bfr(b) << 16); }
__device__ __forceinline__ float bff(ushort u) { return __uint_as_float((uint)u << 16); }
__device__ __forceinline__ float lo16(uint u) { return __uint_as_float(u << 16); }
__device__ __forceinline__ float hi16(uint u) { return __uint_as_float(u & 0xffff0000u); }

// ---------------- k0: weights -> bf16 (+ zero smean) ----------------
__global__ __launch_bounds__(256) void k0_weights(
    const float* __restrict__ w_reg, const float* __restrict__ w_mask,
    const float* __restrict__ w_off, const float* __restrict__ w_mod,
    float* __restrict__ ws) {
  int i = blockIdx.x * 256 + threadIdx.x;
  const int nwt = 10 * 65536;
  const int total = nwt + 9 * 32 * 256;   // 729088
  if (i >= total) {
    int z = i - total;
    if (z < 2048) ws[SMEAN_WS + z] = 0.f;
    return;
  }
  float v;
  if (i < 9 * 65536) {
    int kk = i >> 16, o = (i >> 8) & 255, c = i & 255;
    v = w_reg[(o * C_ + c) * 9 + kk];
  } else if (i < nwt) {
    v = w_mask[i - 9 * 65536];
  } else {
    int e = i - nwt;
    int s = e >> 13, r = e & 8191;
    int o2 = r >> 8, c = r & 255;
    if (o2 < 18)      v = w_off[(o2 * C_ + c) * 9 + s];
    else if (o2 < 27) v = w_mod[((o2 - 18) * C_ + c) * 9 + s];
    else              v = 0.f;
  }
  ((ushort*)(ws + WT2_WS))[i] = (ushort)bfr(v);
}

// ---------------- k0b: x NCHW f32 -> NHWC bf16 ----------------
__global__ __launch_bounds__(256) void k0b_nhwc(const float* __restrict__ x,
                                                float* __restrict__ ws) {
  __shared__ float tile[64][65];
  int b = blockIdx.x >> 6, hw0 = (blockIdx.x & 63) << 6;
  int t = threadIdx.x;
  uint* xb = (uint*)(ws + XB_WS) + ((size_t)b << 19);
  int rr = t >> 6, cc = t & 63;
  int e = t & 7, hwp = t >> 3;
  for (int cg = 0; cg < 4; cg++) {
    __syncthreads();
    const float* xp = x + ((size_t)(b * 256 + cg * 64 + rr)) * HWSZ + hw0 + cc;
    #pragma unroll
    for (int r0 = 0; r0 < 64; r0 += 4)
      tile[r0 + rr][cc] = xp[(size_t)r0 * HWSZ];
    __syncthreads();
    #pragma unroll
    for (int h2 = 0; h2 < 2; h2++) {
      int hw_l = h2 * 32 + hwp;
      int c2 = e * 8;
      uint4 val;
      val.x = pk2(tile[c2][hw_l], tile[c2 + 1][hw_l]);
      val.y = pk2(tile[c2 + 2][hw_l], tile[c2 + 3][hw_l]);
      val.z = pk2(tile[c2 + 4][hw_l], tile[c2 + 5][hw_l]);
      val.w = pk2(tile[c2 + 6][hw_l], tile[c2 + 7][hw_l]);
      *(uint4*)&xb[(size_t)(hw0 + hw_l) * 128 + cg * 32 + e * 4] = val;
    }
  }
}

// ---------------- k2: fully pipelined fused kernel ----------------
// 512 thr (8 waves) per (b,h) row. Double-buffered vbuf, 1 barrier/tap.
// Taps: phase A = 9 im2col shifts (off/mod conv); phase B = 9 deform taps + mask tap.
__global__ __launch_bounds__(512, 4) void k2_fused(
    const float* __restrict__ b_off, const float* __restrict__ b_mod,
    const float* __restrict__ b_reg, const float* __restrict__ b_mask,
    float* __restrict__ ws, float* __restrict__ out) {
  __shared__ uint vb[2][64 * 128];     // 2 x 32 KB
  __shared__ float offmod[27 * 64];    // 6.9 KB

  int bl = ((blockIdx.x & 7) << 6) | (blockIdx.x >> 3);   // XCD k -> image k
  int b = bl >> 6, h = bl & 63;
  int t = threadIdx.x;
  int lane = t & 63, w = t >> 6;
  const int hwid = (w << 1) | (lane >> 5);   // 0..15
  const int cl = lane & 31;
  const ushort* xb2 = (const ushort*)(ws + XB_WS) + ((size_t)b << 20);
  const ushort* wt2 = (const ushort*)(ws + WT2_WS);
  const ushort* wom = wt2 + 10 * 65536;
  const int fr = lane & 15, fq = lane >> 4;

  int nrow[4]; uint widx[4];
  #pragma unroll
  for (int p = 0; p < 4; p++) {
    nrow[p] = p * 16 + hwid;
    widx[p] = (uint)nrow[p] * 128u + (((uint)cl * 4u) ^ ((uint)(nrow[p] & 7) << 2));
  }

  auto loadShift = [&](int s, uint4* d) {
    int row = h + s / 3 - 1;
    #pragma unroll
    for (int p = 0; p < 4; p++) {
      int col = nrow[p] + s % 3 - 1;
      uint4 v = make_uint4(0, 0, 0, 0);
      if (((unsigned)row < 64u) && ((unsigned)col < 64u))
        v = *(const uint4*)(xb2 + ((size_t)(row * 64 + col)) * 256 + cl * 8);
      d[p] = v;
    }
  };
  auto makeRecs = [&](int kk, int p, float* wg, int* ix) {
    int n = nrow[p];
    float dy = offmod[(2 * kk) * 64 + n];
    float dx = offmod[(2 * kk + 1) * 64 + n];
    float md = offmod[(18 + kk) * 64 + n];
    float py = (float)(h + kk / 3 - 1) + dy;
    float px = (float)(n + kk % 3 - 1) + dx;
    float fy = floorf(py), fx = floorf(px);
    float ly = py - fy, lx = px - fx;
    int y0 = (int)fy, x0 = (int)fx;
    int y1 = y0 + 1, x1 = x0 + 1;
    float vy0 = ((unsigned)y0 < 64u) ? 1.f : 0.f;
    float vy1 = ((unsigned)y1 < 64u) ? 1.f : 0.f;
    float vx0 = ((unsigned)x0 < 64u) ? 1.f : 0.f;
    float vx1 = ((unsigned)x1 < 64u) ? 1.f : 0.f;
    int cy0 = min(max(y0, 0), 63), cy1 = min(max(y1, 0), 63);
    int cx0 = min(max(x0, 0), 63), cx1 = min(max(x1, 0), 63);
    ix[0] = cy0 * 64 + cx0; wg[0] = (1.f - ly) * (1.f - lx) * md * vy0 * vx0;
    ix[1] = cy0 * 64 + cx1; wg[1] = (1.f - ly) * lx * md * vy0 * vx1;
    ix[2] = cy1 * 64 + cx0; wg[2] = ly * (1.f - lx) * md * vy1 * vx0;
    ix[3] = cy1 * 64 + cx1; wg[3] = ly * lx * md * vy1 * vx1;
  };
  auto combine = [&](const uint4* d, const float* wg) -> uint4 {
    float a0 = 0.f, a1 = 0.f, a2 = 0.f, a3 = 0.f, a4 = 0.f, a5 = 0.f, a6 = 0.f, a7 = 0.f;
    #pragma unroll
    for (int cr = 0; cr < 4; cr++) {
      uint4 dd = d[cr]; float wv = wg[cr];
      a0 = fmaf(wv, lo16(dd.x), a0); a1 = fmaf(wv, hi16(dd.x), a1);
      a2 = fmaf(wv, lo16(dd.y), a2); a3 = fmaf(wv, hi16(dd.y), a3);
      a4 = fmaf(wv, lo16(dd.z), a4); a5 = fmaf(wv, hi16(dd.z), a5);
      a6 = fmaf(wv, lo16(dd.w), a6); a7 = fmaf(wv, hi16(dd.w), a7);
    }
    return make_uint4(pk2(a0, a1), pk2(a2, a3), pk2(a4, a5), pk2(a6, a7));
  };

  // ======== Phase A: off/mod conv, 9 shifts, dbuf pipeline ========
  f32x4 aom = (f32x4)0.f;
  const int m0 = w >> 2, nt0 = w & 3;
  {
    uint4 sd[4];
    loadShift(0, sd);
    #pragma unroll
    for (int p = 0; p < 4; p++) *(uint4*)&vb[0][widx[p]] = sd[p];
    __syncthreads();
    for (int s = 0; s < 9; s++) {
      if (s < 8) loadShift(s + 1, sd);
      const uint cur = s & 1;
      const ushort* wp = wom + (size_t)s * 8192;
      for (int ks = 0; ks < 8; ks++) {
        short8 af = *(const short8*)(wp + (m0 * 16 + fr) * 256 + ks * 32 + fq * 8);
        int bn = nt0 * 16 + fr;
        uint idx = (uint)bn * 128u + (((uint)(ks * 16 + fq * 4)) ^ ((uint)(bn & 7) << 2));
        short8 bf = *(const short8*)&vb[cur][idx];
        aom = __builtin_amdgcn_mfma_f32_16x16x32_bf16(af, bf, aom, 0, 0, 0);
      }
      if (s < 8) {
        #pragma unroll
        for (int p = 0; p < 4; p++) *(uint4*)&vb[(s & 1) ^ 1][widx[p]] = sd[p];
      }
      __syncthreads();
    }
  }
  #pragma unroll
  for (int r = 0; r < 4; r++) {
    int o = m0 * 16 + fq * 4 + r;
    int nn = nt0 * 16 + fr;
    if (o < 18) {
      offmod[o * 64 + nn] = aom[r] + b_off[o];
    } else if (o < 27) {
      float v = aom[r] + b_mod[o - 18];
      offmod[o * 64 + nn] = 2.f / (1.f + expf(-v));
    }
  }
  __syncthreads();

  // ======== Phase B: 9 deform taps + mask tap, dbuf pipeline ========
  f32x4 acc[2][4];
  #pragma unroll
  for (int mt = 0; mt < 2; mt++)
    #pragma unroll
    for (int nt = 0; nt < 4; nt++) acc[mt][nt] = (f32x4)0.f;
  const int o0 = w << 5;
  float* sme = ws + SMEAN_WS + b * 256;
  ushort* mws = (ushort*)(ws + M_WS);

  // prologue: tap 0 gather -> vb[0]
  {
    #pragma unroll
    for (int p = 0; p < 4; p++) {
      float wg[4]; int ix[4];
      makeRecs(0, p, wg, ix);
      uint4 d[4];
      #pragma unroll
      for (int cr = 0; cr < 4; cr++)
        d[cr] = *(const uint4*)(xb2 + (size_t)ix[cr] * 256 + cl * 8);
      *(uint4*)&vb[0][widx[p]] = combine(d, wg);
    }
  }
  __syncthreads();

  for (int kk = 0; kk < 10; kk++) {
    const uint cur = kk & 1, nxt = cur ^ 1;
    const ushort* wtap = wt2 + (size_t)kk * 65536;
    const int nk = kk + 1;
    uint4 d[8];
    float wg01[8];
    // issue prefetch loads for next tap (p = 0,1)
    if (nk < 9) {
      #pragma unroll
      for (int p = 0; p < 2; p++) {
        float wg[4]; int ix[4];
        makeRecs(nk, p, wg, ix);
        #pragma unroll
        for (int cr = 0; cr < 4; cr++) {
          d[p * 4 + cr] = *(const uint4*)(xb2 + (size_t)ix[cr] * 256 + cl * 8);
          wg01[p * 4 + cr] = wg[cr];
        }
      }
    } else if (nk == 9) {
      #pragma unroll
      for (int p = 0; p < 2; p++)
        d[p * 4] = *(const uint4*)(xb2 + ((size_t)(h * 64 + nrow[p])) * 256 + cl * 8);
    }
    // GEMM first half (ks 0..3)
    for (int ks = 0; ks < 4; ks++) {
      short8 af0 = *(const short8*)(wtap + (o0 + fr) * 256 + ks * 32 + fq * 8);
      short8 af1 = *(const short8*)(wtap + (o0 + 16 + fr) * 256 + ks * 32 + fq * 8);
      #pragma unroll
      for (int nt = 0; nt < 4; nt++) {
        int bn = nt * 16 + fr;
        uint idx = (uint)bn * 128u + (((uint)(ks * 16 + fq * 4)) ^ ((uint)(bn & 7) << 2));
        short8 bf = *(const short8*)&vb[cur][idx];
        acc[0][nt] = __builtin_amdgcn_mfma_f32_16x16x32_bf16(af0, bf, acc[0][nt], 0, 0, 0);
        acc[1][nt] = __builtin_amdgcn_mfma_f32_16x16x32_bf16(af1, bf, acc[1][nt], 0, 0, 0);
      }
    }
    // combine+write p0,1 ; issue loads p2,3
    if (nk < 9) {
      *(uint4*)&vb[nxt][widx[0]] = combine(&d[0], &wg01[0]);
      *(uint4*)&vb[nxt][widx[1]] = combine(&d[4], &wg01[4]);
      #pragma unroll
      for (int p = 2; p < 4; p++) {
        float wg[4]; int ix[4];
        makeRecs(nk, p, wg, ix);
        #pragma unroll
        for (int cr = 0; cr < 4; cr++) {
          d[(p - 2) * 4 + cr] = *(const uint4*)(xb2 + (size_t)ix[cr] * 256 + cl * 8);
          wg01[(p - 2) * 4 + cr] = wg[cr];
        }
      }
    } else if (nk == 9) {
      *(uint4*)&vb[nxt][widx[0]] = d[0];
      *(uint4*)&vb[nxt][widx[1]] = d[4];
      #pragma unroll
      for (int p = 2; p < 4; p++)
        d[(p - 2) * 4] = *(const uint4*)(xb2 + ((size_t)(h * 64 + nrow[p])) * 256 + cl * 8);
    }
    // GEMM second half (ks 4..7)
    for (int ks = 4; ks < 8; ks++) {
      short8 af0 = *(const short8*)(wtap + (o0 + fr) * 256 + ks * 32 + fq * 8);
      short8 af1 = *(const short8*)(wtap + (o0 + 16 + fr) * 256 + ks * 32 + fq * 8);
      #pragma unroll
      for (int nt = 0; nt < 4; nt++) {
        int bn = nt * 16 + fr;
        uint idx = (uint)bn * 128u + (((uint)(ks * 16 + fq * 4)) ^ ((uint)(bn & 7) << 2));
        short8 bf = *(const short8*)&vb[cur][idx];
        acc[0][nt] = __builtin_amdgcn_mfma_f32_16x16x32_bf16(af0, bf, acc[0][nt], 0, 0, 0);
        acc[1][nt] = __builtin_amdgcn_mfma_f32_16x16x32_bf16(af1, bf, acc[1][nt], 0, 0, 0);
      }
    }
    // write p2,3 for next tap
    if (nk < 9) {
      *(uint4*)&vb[nxt][widx[2]] = combine(&d[0], &wg01[0]);
      *(uint4*)&vb[nxt][widx[3]] = combine(&d[4], &wg01[4]);
    } else if (nk == 9) {
      *(uint4*)&vb[nxt][widx[2]] = d[0];
      *(uint4*)&vb[nxt][widx[3]] = d[4];
    }
    // f epilogue after tap 8 (deform conv complete)
    if (kk == 8) {
      #pragma unroll
      for (int mt = 0; mt < 2; mt++)
        #pragma unroll
        for (int r = 0; r < 4; r++) {
          int o = o0 + mt * 16 + fq * 4 + r;
          float bo = b_reg[o];
          float* op = out + (size_t)(b * C_ + o) * HWSZ + h * 64;
          float so = 0.f;
          #pragma unroll
          for (int nt = 0; nt < 4; nt++) {
            float fv = acc[mt][nt][r] + bo;
            op[nt * 16 + fr] = fv;
            so += fv;
            acc[mt][nt][r] = 0.f;
          }
          so += __shfl_xor(so, 1);
          so += __shfl_xor(so, 2);
          so += __shfl_xor(so, 4);
          so += __shfl_xor(so, 8);
          if (fr == 0) atomicAdd(&sme[o], so);
        }
    }
    if (kk < 9) __syncthreads();
  }

  // mask epilogue (acc holds mask 1x1 conv)
  #pragma unroll
  for (int mt = 0; mt < 2; mt++)
    #pragma unroll
    for (int r = 0; r < 4; r++) {
      int o = o0 + mt * 16 + fq * 4 + r;
      float bm = b_mask[o];
      ushort* mp = mws + (size_t)(b * C_ + o) * HWSZ + h * 64;
      #pragma unroll
      for (int nt = 0; nt < 4; nt++) {
        float mv = fminf(fmaxf((acc[mt][nt][r] + bm) * (1.f / 6.f) + 0.5f, 0.f), 1.f);
        mp[nt * 16 + fr] = (ushort)bfr(mv);
      }
    }
}

// ---------------- k4: SE MLP (reads channel SUMS) ----------------
__global__ __launch_bounds__(256) void k4_se(
    const float* __restrict__ w_se1, const float* __restrict__ b_se1,
    const float* __restrict__ w_se2, const float* __restrict__ b_se2,
    float* __restrict__ ws) {
  __shared__ float sm[2048];
  __shared__ float s1[512];
  int t = threadIdx.x;
  for (int e = t; e < 2048; e += 256) sm[e] = ws[SMEAN_WS + e] * (1.f / HWSZ);
  __syncthreads();
  for (int e = t; e < 512; e += 256) {
    int b = e >> 6, cr = e & 63;
    float a = b_se1[cr];
    for (int c = 0; c < 256; c++) a += sm[b * 256 + c] * w_se1[cr * 256 + c];
    s1[e] = fmaxf(a, 0.f);
  }
  __syncthreads();
  for (int e = t; e < 2048; e += 256) {
    int b = e >> 8, c = e & 255;
    float a = b_se2[c];
    for (int cr = 0; cr < 64; cr++) a += s1[b * 64 + cr] * w_se2[c * 64 + cr];
    ws[SSCALE_WS + e] = 1.f / (1.f + expf(-a));
  }
}

// ---------------- k5: final combine: out = f*s*m + x ----------------
__global__ __launch_bounds__(256) void k5_final(const float* __restrict__ x,
                                                const float* __restrict__ ws,
                                                float* __restrict__ out) {
  const ushort* mws = (const ushort*)(ws + M_WS);
  int i4 = blockIdx.x * 256 + threadIdx.x;
  const int total = B_ * C_ * HWSZ / 4;
  for (; i4 < total; i4 += gridDim.x * 256) {
    int i = i4 * 4;
    int bc = i >> 12;
    float s = ws[SSCALE_WS + bc];
    float4 f = *(const float4*)&out[i];
    uint2 mu = *(const uint2*)&mws[i];
    float4 xv = *(const float4*)&x[i];
    float4 r;
    r.x = f.x * s * bff((ushort)(mu.x & 0xffffu)) + xv.x;
    r.y = f.y * s * bff((ushort)(mu.x >> 16)) + xv.y;
    r.z = f.z * s * bff((ushort)(mu.y & 0xffffu)) + xv.z;
    r.w = f.w * s * bff((ushort)(mu.y >> 16)) + xv.w;
    *(float4*)&out[i] = r;
  }
}

extern "C" void kernel_launch(void* const* d_in, const int* in_sizes, int n_in,
                              void* d_out, int out_size, void* d_ws, size_t ws_size,
                              hipStream_t stream) {
  const float* x      = (const float*)d_in[0];
  const float* w_off  = (const float*)d_in[1];
  const float* b_off  = (const float*)d_in[2];
  const float* w_mod  = (const float*)d_in[3];
  const float* b_mod  = (const float*)d_in[4];
  const float* w_reg  = (const float*)d_in[5];
  const float* b_reg  = (const float*)d_in[6];
  const float* w_se1  = (const float*)d_in[7];
  const float* b_se1  = (const float*)d_in[8];
  const float* w_se2  = (const float*)d_in[9];
  const float* b_se2  = (const float*)d_in[10];
  const float* w_mask = (const float*)d_in[11];
  const float* b_mask = (const float*)d_in[12];
  float* out = (float*)d_out;
  float* ws  = (float*)d_ws;

  k0_weights<<<dim3(2856), dim3(256), 0, stream>>>(w_reg, w_mask, w_off, w_mod, ws);
  k0b_nhwc<<<dim3(512), dim3(256), 0, stream>>>(x, ws);
  k2_fused<<<dim3(512), dim3(512), 0, stream>>>(b_off, b_mod, b_reg, b_mask, ws, out);
  k4_se<<<dim3(1), dim3(256), 0, stream>>>(w_se1, b_se1, w_se2, b_se2, ws);
  k5_final<<<dim3(2048), dim3(256), 0, stream>>>(x, ws, out);
}